// Round 1
// baseline (1615.586 us; speedup 1.0000x reference)
//
#include <hip/hip_runtime.h>
#include <hip/hip_bf16.h>
#include <stdint.h>

#define DEVFN __device__ __forceinline__

typedef __bf16 bf16x8 __attribute__((ext_vector_type(8)));
typedef float  f32x4  __attribute__((ext_vector_type(4)));

// ---------- bf16 helpers (raw ushort storage) ----------
DEVFN ushort f2bf(float x) {
  uint32_t u = __builtin_bit_cast(uint32_t, x);
  u += 0x7fffu + ((u >> 16) & 1u);   // RNE
  return (ushort)(u >> 16);
}
DEVFN float bf2f(ushort h) {
  uint32_t u = ((uint32_t)h) << 16;
  return __builtin_bit_cast(float, u);
}

// ---------- async global->LDS, 16B per lane ----------
DEVFN void gload16(const void* g, void* l) {
  __builtin_amdgcn_global_load_lds(
      (const __attribute__((address_space(1))) void*)g,
      (__attribute__((address_space(3))) void*)l, 16, 0, 0);
}

// ---------- instance-norm stats: mean + rstd (ddof=1, eps inside sqrt) ----------
__global__ void stats_kernel(const float* __restrict__ content,
                             const float* __restrict__ style,
                             float* __restrict__ mu_c, float* __restrict__ r_c,
                             float* __restrict__ mu_s, float* __restrict__ r_s) {
  const int c = blockIdx.x;
  const int sel = blockIdx.y;
  const float* X = (sel ? style : content) + (size_t)c * 4096;
  float s = 0.f, s2 = 0.f;
  for (int i = threadIdx.x; i < 4096; i += 256) {
    float x = X[i];
    s += x; s2 += x * x;
  }
  for (int off = 32; off > 0; off >>= 1) {
    s  += __shfl_xor(s, off);
    s2 += __shfl_xor(s2, off);
  }
  __shared__ float ls[8];
  const int wv = threadIdx.x >> 6;
  if ((threadIdx.x & 63) == 0) { ls[wv] = s; ls[4 + wv] = s2; }
  __syncthreads();
  if (threadIdx.x == 0) {
    float S  = ls[0] + ls[1] + ls[2] + ls[3];
    float S2 = ls[4] + ls[5] + ls[6] + ls[7];
    float mean = S * (1.f / 4096.f);
    float var  = (S2 - 4096.f * mean * mean) * (1.f / 4095.f);
    float r    = rsqrtf(var + 1e-5f);
    if (sel) { mu_s[c] = mean; r_s[c] = r; }
    else     { mu_c[c] = mean; r_c[c] = r; }
  }
}

// ---------- split fp32 [C][N] into bf16 hi/lo transposed [N][C] ----------
__global__ void split_transpose_kernel(const float* __restrict__ X,
                                       ushort* __restrict__ Xh,
                                       ushort* __restrict__ Xl) {
  __shared__ float tile[64][65];
  const int n0 = blockIdx.x * 64;
  const int c0 = blockIdx.y * 64;
  const int tq = threadIdx.x >> 6;   // 0..3
  const int tl = threadIdx.x & 63;
#pragma unroll
  for (int r = 0; r < 16; ++r) {
    int c = r * 4 + tq;
    tile[c][tl] = X[(size_t)(c0 + c) * 4096 + n0 + tl];
  }
  __syncthreads();
#pragma unroll
  for (int r = 0; r < 16; ++r) {
    int n = r * 4 + tq;
    float x = tile[tl][n];
    ushort h = f2bf(x);
    size_t o = (size_t)(n0 + n) * 512 + c0 + tl;
    Xh[o] = h;
    Xl[o] = f2bf(x - bf2f(h));
  }
}

// ---------- fold norm into weights: W' = W*diag(r), b' = b - W' mu ----------
__global__ void prep_weights_kernel(const float* __restrict__ w1, const float* __restrict__ b1,
                                    const float* __restrict__ w2, const float* __restrict__ b2,
                                    const float* __restrict__ w3,
                                    const float* __restrict__ mu_c, const float* __restrict__ r_c,
                                    const float* __restrict__ mu_s, const float* __restrict__ r_s,
                                    ushort* __restrict__ W1h, ushort* __restrict__ W1l,
                                    ushort* __restrict__ W2h, ushort* __restrict__ W2l,
                                    ushort* __restrict__ W3b,
                                    float* __restrict__ bias1, float* __restrict__ bias2) {
  const int o = blockIdx.x;
  const int which = blockIdx.y;
  if (which == 2) {
    for (int cc = threadIdx.x; cc < 512; cc += 256)
      W3b[o * 512 + cc] = f2bf(w3[o * 512 + cc]);
    return;
  }
  const float* W  = which ? w2 : w1;
  const float* mu = which ? mu_s : mu_c;
  const float* rr = which ? r_s : r_c;
  ushort* Wh = which ? W2h : W1h;
  ushort* Wl = which ? W2l : W1l;
  float dot = 0.f;
  for (int cc = threadIdx.x; cc < 512; cc += 256) {
    float wv = W[o * 512 + cc] * rr[cc];
    ushort h = f2bf(wv);
    Wh[o * 512 + cc] = h;
    Wl[o * 512 + cc] = f2bf(wv - bf2f(h));
    dot += wv * mu[cc];
  }
  for (int off = 32; off > 0; off >>= 1) dot += __shfl_xor(dot, off);
  __shared__ float ls[4];
  if ((threadIdx.x & 63) == 0) ls[threadIdx.x >> 6] = dot;
  __syncthreads();
  if (threadIdx.x == 0) {
    float d = ls[0] + ls[1] + ls[2] + ls[3];
    float bb = (which ? b2[o] : b1[o]) - d;
    (which ? bias2 : bias1)[o] = bb;
  }
}

// ---------- uniform B^T-pattern GEMM: out[i][j] = sum_k A[i][k]*B[j][k] ----------
// A: [M][K] bf16 (hi + optional lo), B: [N][K] bf16 (hi + optional lo), row-major.
// STORE: 0 = f32 -> outF ; 1 = bf16 -> outH ; 2 = split pair -> outH/outL.
// 128x128 tile, BK=64, 4 waves (2x2 of 64x64), 16x16x32 bf16 MFMA, m97 structure.
template <int STORE, bool SPLIT, bool BIASI, bool BIASJ>
__global__ __launch_bounds__(256) void gemm_bt_kernel(
    const ushort* __restrict__ Ah, const ushort* __restrict__ Al,
    const ushort* __restrict__ Bh, const ushort* __restrict__ Bl,
    float* __restrict__ outF, ushort* __restrict__ outH, ushort* __restrict__ outL,
    const float* __restrict__ biasI, const float* __restrict__ biasJ,
    int M, int N, int K) {
  __shared__ ushort lsAh[128 * 64];
  __shared__ ushort lsBh[128 * 64];
  __shared__ ushort lsAl[SPLIT ? 128 * 64 : 8];
  __shared__ ushort lsBl[SPLIT ? 128 * 64 : 8];
  const int t    = threadIdx.x;
  const int lane = t & 63;
  const int wv   = t >> 6;
  const int wi = wv >> 1, wj = wv & 1;
  const int i0 = blockIdx.x * 128;
  const int j0 = blockIdx.y * 128;

  f32x4 acc[4][4] = {};

  for (int kt = 0; kt < K; kt += 64) {
#pragma unroll
    for (int q = 0; q < 4; ++q) {
      const int ci = q * 256 + wv * 64 + lane;   // 16B chunk index within tile
      const int r  = ci >> 3;                    // row in 128
      const int c  = (ci & 7) << 3;              // col (bf16 elems) in 64
      const size_t gA = (size_t)(i0 + r) * K + kt + c;
      const size_t gB = (size_t)(j0 + r) * K + kt + c;
      const int lo_ = (q * 256 + wv * 64) * 8;   // wave-uniform LDS elem offset
      gload16(Ah + gA, &lsAh[lo_]);
      gload16(Bh + gB, &lsBh[lo_]);
      if constexpr (SPLIT) {
        gload16(Al + gA, &lsAl[lo_]);
        gload16(Bl + gB, &lsBl[lo_]);
      }
    }
    __syncthreads();
#pragma unroll
    for (int kk = 0; kk < 2; ++kk) {
      const int ko = kk * 32 + (lane >> 4) * 8;
      const int ra = wi * 64 + (lane & 15);
      const int rb = wj * 64 + (lane & 15);
      bf16x8 aH[4], bH[4];
#pragma unroll
      for (int x = 0; x < 4; ++x) {
        aH[x] = *(const bf16x8*)&lsAh[(ra + x * 16) * 64 + ko];
        bH[x] = *(const bf16x8*)&lsBh[(rb + x * 16) * 64 + ko];
      }
      if constexpr (SPLIT) {
        bf16x8 aL[4], bL[4];
#pragma unroll
        for (int x = 0; x < 4; ++x) {
          aL[x] = *(const bf16x8*)&lsAl[(ra + x * 16) * 64 + ko];
          bL[x] = *(const bf16x8*)&lsBl[(rb + x * 16) * 64 + ko];
        }
#pragma unroll
        for (int mi = 0; mi < 4; ++mi)
#pragma unroll
          for (int ni = 0; ni < 4; ++ni) {
            acc[mi][ni] = __builtin_amdgcn_mfma_f32_16x16x32_bf16(aH[mi], bH[ni], acc[mi][ni], 0, 0, 0);
            acc[mi][ni] = __builtin_amdgcn_mfma_f32_16x16x32_bf16(aH[mi], bL[ni], acc[mi][ni], 0, 0, 0);
            acc[mi][ni] = __builtin_amdgcn_mfma_f32_16x16x32_bf16(aL[mi], bH[ni], acc[mi][ni], 0, 0, 0);
          }
      } else {
#pragma unroll
        for (int mi = 0; mi < 4; ++mi)
#pragma unroll
          for (int ni = 0; ni < 4; ++ni)
            acc[mi][ni] = __builtin_amdgcn_mfma_f32_16x16x32_bf16(aH[mi], bH[ni], acc[mi][ni], 0, 0, 0);
      }
    }
    __syncthreads();
  }

  // epilogue: C/D layout col=lane&15, row=(lane>>4)*4+r   [m89-verified]
  const int col = lane & 15;
  const int rw0 = (lane >> 4) * 4;
#pragma unroll
  for (int mi = 0; mi < 4; ++mi) {
#pragma unroll
    for (int ni = 0; ni < 4; ++ni) {
      const int ig0 = i0 + wi * 64 + mi * 16 + rw0;
      const int jg  = j0 + wj * 64 + ni * 16 + col;
      float bj = 0.f;
      if constexpr (BIASJ) bj = biasJ[jg];
#pragma unroll
      for (int r = 0; r < 4; ++r) {
        float v = acc[mi][ni][r] + bj;
        if constexpr (BIASI) v += biasI[ig0 + r];
        const size_t oo = (size_t)(ig0 + r) * N + jg;
        if constexpr (STORE == 0) {
          outF[oo] = v;
        } else if constexpr (STORE == 1) {
          outH[oo] = f2bf(v);
        } else {
          ushort h = f2bf(v);
          outH[oo] = h;
          outL[oo] = f2bf(v - bf2f(h));
        }
      }
    }
  }
}

// ---------- column softmax stats over St[n][m], softmax dim = n (rows) ----------
__global__ void softmax_partial_kernel(const float* __restrict__ St,
                                       float* __restrict__ pmax, float* __restrict__ psum) {
  const int m  = blockIdx.x * 256 + threadIdx.x;
  const int n0 = blockIdx.y * 512;
  float mx = -3.0e38f, sm = 0.f;
  for (int n = n0; n < n0 + 512; ++n) {
    float x = St[(size_t)n * 4096 + m];
    if (x > mx) { sm = sm * __expf(mx - x) + 1.f; mx = x; }
    else        { sm += __expf(x - mx); }
  }
  pmax[blockIdx.y * 4096 + m] = mx;
  psum[blockIdx.y * 4096 + m] = sm;
}

__global__ void softmax_finalize_kernel(const float* __restrict__ pmax,
                                        const float* __restrict__ psum,
                                        float* __restrict__ cmax, float* __restrict__ cinv) {
  const int m = blockIdx.x * 256 + threadIdx.x;
  float M = -3.0e38f;
#pragma unroll
  for (int p = 0; p < 8; ++p) M = fmaxf(M, pmax[p * 4096 + m]);
  float Z = 0.f;
#pragma unroll
  for (int p = 0; p < 8; ++p) Z += psum[p * 4096 + m] * __expf(pmax[p * 4096 + m] - M);
  cmax[m] = M;
  cinv[m] = 1.f / Z;
}

// ---------- P[n][m] = bf16(exp(St - cmax[m]) * cinv[m]) ----------
__global__ void exp_kernel(const float* __restrict__ St, const float* __restrict__ cmax,
                           const float* __restrict__ cinv, ushort* __restrict__ P) {
  const int total4 = 4096 * 1024;
  for (int idx = blockIdx.x * 256 + threadIdx.x; idx < total4; idx += gridDim.x * 256) {
    const int m0 = (idx & 1023) << 2;
    float4 s = ((const float4*)St)[idx];
    ushort4 p;
    p.x = f2bf(__expf(s.x - cmax[m0 + 0]) * cinv[m0 + 0]);
    p.y = f2bf(__expf(s.y - cmax[m0 + 1]) * cinv[m0 + 1]);
    p.z = f2bf(__expf(s.z - cmax[m0 + 2]) * cinv[m0 + 2]);
    p.w = f2bf(__expf(s.w - cmax[m0 + 3]) * cinv[m0 + 3]);
    ((ushort4*)P)[idx] = p;
  }
}

// ---------- host ----------
extern "C" void kernel_launch(void* const* d_in, const int* in_sizes, int n_in,
                              void* d_out, int out_size, void* d_ws, size_t ws_size,
                              hipStream_t stream) {
  const float* content = (const float*)d_in[0];
  const float* style   = (const float*)d_in[1];
  const float* w1 = (const float*)d_in[2];
  const float* b1 = (const float*)d_in[3];
  const float* w2 = (const float*)d_in[4];
  const float* b2 = (const float*)d_in[5];
  const float* w3 = (const float*)d_in[6];
  const float* b3 = (const float*)d_in[7];
  float* out = (float*)d_out;
  (void)in_sizes; (void)n_in; (void)out_size; (void)ws_size;

  char* ws = (char*)d_ws;
  size_t off = 0;
  auto alloc = [&](size_t bytes) -> char* {
    char* p = ws + off;
    off += (bytes + 255) & ~(size_t)255;
    return p;
  };
  float*  muc   = (float*)alloc(512 * 4);
  float*  rc    = (float*)alloc(512 * 4);
  float*  mus   = (float*)alloc(512 * 4);
  float*  rs    = (float*)alloc(512 * 4);
  float*  bias1 = (float*)alloc(512 * 4);
  float*  bias2 = (float*)alloc(512 * 4);
  float*  cmax  = (float*)alloc(4096 * 4);
  float*  cinv  = (float*)alloc(4096 * 4);
  float*  pmax  = (float*)alloc(8 * 4096 * 4);
  float*  psum  = (float*)alloc(8 * 4096 * 4);
  ushort* W1h   = (ushort*)alloc(512 * 512 * 2);
  ushort* W1l   = (ushort*)alloc(512 * 512 * 2);
  ushort* W2h   = (ushort*)alloc(512 * 512 * 2);
  ushort* W2l   = (ushort*)alloc(512 * 512 * 2);
  ushort* W3b   = (ushort*)alloc(512 * 512 * 2);
  ushort* Xct_h = (ushort*)alloc((size_t)4096 * 512 * 2);
  ushort* Xct_l = (ushort*)alloc((size_t)4096 * 512 * 2);
  ushort* Xst_h = (ushort*)alloc((size_t)4096 * 512 * 2);
  ushort* Xst_l = (ushort*)alloc((size_t)4096 * 512 * 2);
  ushort* qth   = (ushort*)alloc((size_t)4096 * 512 * 2);
  ushort* qtl   = (ushort*)alloc((size_t)4096 * 512 * 2);
  ushort* kth   = (ushort*)alloc((size_t)4096 * 512 * 2);
  ushort* ktl   = (ushort*)alloc((size_t)4096 * 512 * 2);
  ushort* vb    = (ushort*)alloc((size_t)512 * 4096 * 2);
  float*  St    = (float*)alloc((size_t)4096 * 4096 * 4);
  ushort* Pb    = (ushort*)alloc((size_t)4096 * 4096 * 2);

  for (int b = 0; b < 4; ++b) {
    const float* cb = content + (size_t)b * 512 * 4096;
    const float* sb = style   + (size_t)b * 512 * 4096;
    float*       ob = out     + (size_t)b * 512 * 4096;

    stats_kernel<<<dim3(512, 2), 256, 0, stream>>>(cb, sb, muc, rc, mus, rs);
    split_transpose_kernel<<<dim3(64, 8), 256, 0, stream>>>(cb, Xct_h, Xct_l);
    split_transpose_kernel<<<dim3(64, 8), 256, 0, stream>>>(sb, Xst_h, Xst_l);
    prep_weights_kernel<<<dim3(512, 3), 256, 0, stream>>>(
        w1, b1, w2, b2, w3, muc, rc, mus, rs, W1h, W1l, W2h, W2l, W3b, bias1, bias2);

    // q_t[n][c_out] = Xct[n][:] . W1'[c_out][:] + b1'   (split in, split-pair out)
    gemm_bt_kernel<2, true, false, true><<<dim3(32, 4), 256, 0, stream>>>(
        Xct_h, Xct_l, W1h, W1l, nullptr, qth, qtl, nullptr, bias1, 4096, 512, 512);
    // k_t[m][c_out]
    gemm_bt_kernel<2, true, false, true><<<dim3(32, 4), 256, 0, stream>>>(
        Xst_h, Xst_l, W2h, W2l, nullptr, kth, ktl, nullptr, bias2, 4096, 512, 512);
    // v[c_out][m] = W3[c_out][:] . style_t[m][:] + b3   (plain bf16)
    gemm_bt_kernel<1, false, true, false><<<dim3(4, 32), 256, 0, stream>>>(
        W3b, nullptr, Xst_h, nullptr, nullptr, vb, nullptr, b3, nullptr, 512, 4096, 512);
    // St[n][m] = q_t[n][:] . k_t[m][:]   (split, fp32 out)
    gemm_bt_kernel<0, true, false, false><<<dim3(32, 32), 256, 0, stream>>>(
        qth, qtl, kth, ktl, St, nullptr, nullptr, nullptr, nullptr, 4096, 4096, 512);

    softmax_partial_kernel<<<dim3(16, 8), 256, 0, stream>>>(St, pmax, psum);
    softmax_finalize_kernel<<<16, 256, 0, stream>>>(pmax, psum, cmax, cinv);
    exp_kernel<<<4096, 256, 0, stream>>>(St, cmax, cinv, Pb);

    // out[c][n] = v[c][:] . P[n][:]   (plain bf16, fp32 out -> d_out)
    gemm_bt_kernel<0, false, false, false><<<dim3(4, 32), 256, 0, stream>>>(
        vb, nullptr, Pb, nullptr, ob, nullptr, nullptr, nullptr, nullptr, 512, 4096, 4096);
  }
}